// Round 1
// baseline (179.649 us; speedup 1.0000x reference)
//
#include <hip/hip_runtime.h>

// SimpleCRFHead: B=8192 seqs, L=256 steps, S=9 states.
// Design: linear-domain forward algorithm, per-seq power-of-2 rescaling,
// mfma_f32_16x16x16f16 chains B->D->B in-register (layouts match).
// 16 seqs per wave, 512 waves total, 64-thread blocks.

#define B_N 8192
#define L_N 256
#define S_N 9
#define TOT (B_N * L_N * S_N)      // 18,874,368 floats in inputs
#define PL_TOT (B_N * L_N)         // 2,097,152 ints in path

typedef __attribute__((ext_vector_type(4))) float f32x4;
typedef __attribute__((ext_vector_type(4))) _Float16 f16x4;

__device__ __forceinline__ unsigned umin_(unsigned a, unsigned b) {
    return a < b ? a : b;
}

__global__ __launch_bounds__(64) void crf_fwd(
    const float* __restrict__ xg,      // (B, L, 9)
    const int*   __restrict__ path,    // (B, L)
    const float* __restrict__ tran,    // (9, 9)
    const float* __restrict__ initv,   // (9,)
    float*       __restrict__ out)     // (B,)
{
    const int lane = threadIdx.x;       // 0..63
    const int n    = lane & 15;         // seq slot (B/D col); also A row m
    const int nb   = (lane >> 4) * 4;   // state base for this lane's 4 regs
    const int seq  = blockIdx.x * 16 + n;

    __shared__ float ltran[81];
    for (int i = lane; i < 81; i += 64) ltran[i] = tran[i];
    __syncthreads();

    // A fragment: A[m][k] = E^T[m][k] = exp(tran[k][m]); m = lane&15, k = nb+j.
    // Zero-padded rows/cols beyond state 9 keep pad states exactly 0.
    f16x4 afrag;
#pragma unroll
    for (int j = 0; j < 4; ++j) {
        int k = nb + j;
        float v = (k < 9 && n < 9) ? __expf(ltran[k * 9 + n]) : 0.0f;
        afrag[j] = (_Float16)v;
    }

    const unsigned xbase = (unsigned)seq * (L_N * S_N) + (unsigned)nb;
    const unsigned pbase = (unsigned)seq * L_N;

    // ---- t = 0: init + x0
    float x0[4];
    {
        unsigned o = umin_(xbase, (unsigned)(TOT - 4));
#pragma unroll
        for (int j = 0; j < 4; ++j) x0[j] = xg[o + j];
    }
    float beta[4];   // linear-domain alpha, scaled by 2^-c_exp
#pragma unroll
    for (int j = 0; j < 4; ++j) {
        int st = nb + j;
        float iv = initv[st < 9 ? st : 8];
        float a0 = iv + fminf(x0[j], 7.0f);
        beta[j] = (st < 9) ? __expf(a0) : 0.0f;
    }
    const int p0 = path[pbase];
    int pprev = p0;
    float emitacc;
    {
        unsigned ud = (unsigned)(p0 - nb);
        float lo = (ud & 1) ? x0[1] : x0[0];
        float hi = (ud & 1) ? x0[3] : x0[2];
        float sel = (ud & 2) ? hi : lo;
        emitacc = (ud < 4u) ? sel : 0.0f;
    }
    float tranacc = 0.0f;
    int c_exp = 0;

    // ---- prefetch t = 1..8 (depth-8 rotating register buffers)
    float xa[8][4];
    int pa[8];
#pragma unroll
    for (int u = 0; u < 8; ++u) {
        unsigned t = 1u + u;
        unsigned o = umin_(xbase + t * S_N, (unsigned)(TOT - 4));
#pragma unroll
        for (int j = 0; j < 4; ++j) xa[u][j] = xg[o + j];
        pa[u] = path[umin_(pbase + t, (unsigned)(PL_TOT - 1))];
    }

    const f32x4 zeroc = {0.f, 0.f, 0.f, 0.f};

    for (int cc = 0; cc < 32; ++cc) {
#pragma unroll
        for (int u = 0; u < 8; ++u) {
            int t = cc * 8 + 1 + u;
            if (t <= 255) {
                // -- rescale (per-seq max across the 4 quads), convert to f16
                float mx = fmaxf(fmaxf(beta[0], beta[1]), fmaxf(beta[2], beta[3]));
                mx = fmaxf(mx, __shfl_xor(mx, 16));
                mx = fmaxf(mx, __shfl_xor(mx, 32));
                mx = fmaxf(mx, 1e-20f);
                int ex = (int)((__float_as_uint(mx) >> 23) & 0xffu) - 126;
                c_exp += ex;
                float sc = __uint_as_float(((unsigned)(127 - ex)) << 23); // 2^-ex
                f16x4 bfrag;
#pragma unroll
                for (int j = 0; j < 4; ++j) bfrag[j] = (_Float16)(beta[j] * sc);

                // -- D[m][seq] = sum_k E[k][m] * beta[seq][k]
                f32x4 D = __builtin_amdgcn_mfma_f32_16x16x16f16(afrag, bfrag, zeroc, 0, 0, 0);

                const float* xt = xa[u];
                const int p = pa[u];

                // -- path score: emit gather (exactly one quad in range)
                {
                    unsigned ud = (unsigned)(p - nb);
                    float lo = (ud & 1) ? xt[1] : xt[0];
                    float hi = (ud & 1) ? xt[3] : xt[2];
                    float sel = (ud & 2) ? hi : lo;
                    emitacc += (ud < 4u) ? sel : 0.0f;
                }
                // -- transition score (all 4 quads duplicate; scaled 0.25 later)
                tranacc += ltran[pprev * 9 + p];
                pprev = p;

                // -- beta' = D * exp(x)
#pragma unroll
                for (int j = 0; j < 4; ++j) {
                    float e = __expf(fminf(xt[j], 7.0f));
                    beta[j] = D[j] * e;
                }

                // -- prefetch t+8
                unsigned tn = (unsigned)(t + 8);
                unsigned o = umin_(xbase + tn * S_N, (unsigned)(TOT - 4));
#pragma unroll
                for (int j = 0; j < 4; ++j) xa[u][j] = xg[o + j];
                pa[u] = path[umin_(pbase + tn, (unsigned)(PL_TOT - 1))];
            }
        }
    }

    // ---- final: scores = ln(sum_j beta_j) + c_exp*ln2
    float ssum = (beta[0] + beta[1]) + (beta[2] + beta[3]);
    ssum += __shfl_xor(ssum, 16);
    ssum += __shfl_xor(ssum, 32);
    float score = (__log2f(ssum) + (float)c_exp) * 0.69314718055994531f;

    // ---- path_scores = emit_total + tran_total + init[p0]
    float pval = emitacc + 0.25f * tranacc;
    pval += __shfl_xor(pval, 16);
    pval += __shfl_xor(pval, 32);
    pval += initv[p0];

    if (lane < 16) out[(unsigned)blockIdx.x * 16u + (unsigned)lane] = score - pval;
}

extern "C" void kernel_launch(void* const* d_in, const int* in_sizes, int n_in,
                              void* d_out, int out_size, void* d_ws, size_t ws_size,
                              hipStream_t stream) {
    (void)in_sizes; (void)n_in; (void)d_ws; (void)ws_size; (void)out_size;
    const float* xg    = (const float*)d_in[0];
    const int*   path  = (const int*)d_in[1];
    const float* tran  = (const float*)d_in[2];
    const float* initv = (const float*)d_in[3];
    float* out = (float*)d_out;
    crf_fwd<<<B_N / 16, 64, 0, stream>>>(xg, path, tran, initv, out);
}

// Round 3
// 152.979 us; speedup vs baseline: 1.1743x; 1.1743x over previous
//
#include <hip/hip_runtime.h>

// SimpleCRFHead R3: lane-per-sequence f32 forward-backward split.
//  - kernel1 (crf_half): 256 blocks x 64 threads (1 wave/block, 1/CU).
//      blocks [0,128): forward  beta_t, t=0..127   (64 seqs per block, lane=seq)
//      blocks [128,256): backward u_t,  t=255..128
//    9x9 matvec = 81 scalar FMAs vs uniform E=exp(tran) in registers.
//    Lane-local power-of-2 rescale every 8 steps (f32 range: worst growth
//    2^13.3/step * 8 = 2^106 < 2^127 -- safe). NO cross-lane ops in the loop.
//    x staged to LDS via global_load_lds (per-seq contiguous 54-float rows,
//    stride 55 => odd => conflict-free reads), double-buffered.
//    path staged once (stride 129 => (lane+t)%32 banks, conflict-free).
//  - kernel2 (crf_combine): score = ln2*(log2(dot9(beta,u)) + ce_f + ce_b)
//    minus path score partials.  ws usage: 22 * 8192 * 4B = 721 KB.

#define B_N 8192
#define L_N 256
#define S_N 9
#define SEQ_STRIDE 2304      // L_N * S_N
#define HALF 128
#define SPB 6                // steps per x block
#define XW 54                // floats per seq per x block (SPB*9)
#define XSTRIDE 55           // LDS row stride (odd -> no bank conflicts)
#define NBLK 22              // ceil(128/6)
#define PLS 129              // path LDS row stride
#define NDIR_BLOCKS (B_N / 64)

#define LOG2E 1.44269504088896340736f
#define LN2f  0.69314718055994530942f

__device__ __forceinline__ void gl_lds4(const void* g, void* l) {
  __builtin_amdgcn_global_load_lds(
      (const __attribute__((address_space(1))) void*)g,
      (__attribute__((address_space(3))) void*)l, 4, 0, 0);
}

// v_exp_f32 computes 2^x; v_log_f32 computes log2(x)
__device__ __forceinline__ float fexp(float x) {
  return __builtin_amdgcn_exp2f(x * LOG2E);
}

__global__ __launch_bounds__(64) void crf_half(
    const float* __restrict__ xg, const int* __restrict__ path,
    const float* __restrict__ tran, const float* __restrict__ initv,
    float* __restrict__ ws)
{
  __shared__ float lx[2][64 * XSTRIDE];   // 28160 B
  __shared__ int   pl[64 * PLS];          // 33024 B
  __shared__ float ltran[81];             // total 61508 B < 64 KB

  const int lane = threadIdx.x;
  const bool fwd = (int)blockIdx.x < NDIR_BLOCKS;
  const int seq0 = (fwd ? blockIdx.x : blockIdx.x - NDIR_BLOCKS) * 64;
  const int seq  = seq0 + lane;

  for (int i = lane; i < 81; i += 64) ltran[i] = tran[i];

  // ---- stage path: fwd t in [0,127]; bwd t in [127,255]
  {
    const int t0 = fwd ? 0 : 127;
    const int* g = path + (size_t)seq0 * L_N + t0 + lane;
    for (int ss = 0; ss < 64; ++ss) {
      gl_lds4(g,      &pl[ss * PLS]);       // rows t0 .. t0+63
      gl_lds4(g + 64, &pl[ss * PLS + 64]);  // t0+64 .. t0+127
      g += L_N;
    }
    if (!fwd && lane == 0) {
      const int* g2 = path + (size_t)seq0 * L_N + 255;
      for (int ss = 0; ss < 64; ++ss) {
        gl_lds4(g2, &pl[ss * PLS + 128]);   // t=255
        g2 += L_N;
      }
    }
  }

  // ---- stage x block 0
  if (lane < XW) {
    const int fbase = fwd ? 0 : (SEQ_STRIDE - XW);
    const float* g = xg + (size_t)seq0 * SEQ_STRIDE + fbase + lane;
    for (int ss = 0; ss < 64; ++ss) {
      gl_lds4(g, &lx[0][ss * XSTRIDE]);
      g += SEQ_STRIDE;
    }
  }

  // ---- uniform transition coefficients (scalar loads + v_exp, prologue only)
  // fwd: out_j = sum_i E[j][i]*beta_i, E[j][i] = e^{tran[i][j]}
  // bwd: u_i   = sum_j E[i][j]*w_j,    E[i][j] = e^{tran[i][j]}
  float E[9][9];
#pragma unroll
  for (int a = 0; a < 9; ++a)
#pragma unroll
    for (int b = 0; b < 9; ++b)
      E[a][b] = fexp(fwd ? tran[b * 9 + a] : tran[a * 9 + b]);

  float st[9];
  float emit = 0.f, trn = 0.f;
  int ce = 0, pcur = 0;

  asm volatile("s_waitcnt vmcnt(0)" ::: "memory");

  if (!fwd) {
#pragma unroll
    for (int i = 0; i < 9; ++i) st[i] = 1.f;
    pcur = pl[lane * PLS + 128];   // p_255
  }

  const int plbase = lane * PLS;
  const int xrow   = lane * XSTRIDE;

#pragma unroll 1
  for (int b = 0; b < NBLK; ++b) {
    // wait for block b's staging (issued last iteration; long since landed)
    asm volatile("s_waitcnt vmcnt(0)" ::: "memory");

    // prefetch block b+1 into the other buffer
    if (b + 1 < NBLK && lane < XW) {
      const int fb = fwd ? (b + 1) * XW : (SEQ_STRIDE - XW * (b + 2));
      const float* g = xg + (size_t)seq0 * SEQ_STRIDE + fb + lane;
      float* dst = &lx[(b + 1) & 1][0];
      for (int ss = 0; ss < 64; ++ss) {
        gl_lds4(g, dst + ss * XSTRIDE);
        g += SEQ_STRIDE;
      }
    }

    const float* lxb = &lx[b & 1][xrow];

    if (fwd) {
#pragma unroll
      for (int k = 0; k < SPB; ++k) {
        const int t = b * SPB + k;
        if (t >= HALF) break;
        const int off = k * 9;
        float xv[9];
#pragma unroll
        for (int j = 0; j < 9; ++j) xv[j] = lxb[off + j];
        if (t == 0) {
#pragma unroll
          for (int i = 0; i < 9; ++i) st[i] = fexp(initv[i] + xv[i]);
          pcur = pl[plbase];            // p_0
          emit = lxb[off + pcur];
        } else {
          float e[9];
#pragma unroll
          for (int j = 0; j < 9; ++j) e[j] = fexp(xv[j]);
          float acc[9];
#pragma unroll
          for (int i = 0; i < 9; ++i) {
            float a = E[i][0] * st[0];
#pragma unroll
            for (int j = 1; j < 9; ++j) a = fmaf(E[i][j], st[j], a);
            acc[i] = a * e[i];
          }
#pragma unroll
          for (int i = 0; i < 9; ++i) st[i] = acc[i];
          const int p = pl[plbase + t];
          emit += lxb[off + p];
          trn  += ltran[pcur * 9 + p];
          pcur = p;
          if ((t & 7) == 7) {
            float m = st[0];
#pragma unroll
            for (int i = 1; i < 9; ++i) m = fmaxf(m, st[i]);
            const int ex = (int)((__float_as_uint(m) >> 23) & 0xffu) - 126;
            ce += ex;
            const float sc = __uint_as_float((unsigned)(127 - ex) << 23);
#pragma unroll
            for (int i = 0; i < 9; ++i) st[i] *= sc;
          }
        }
      }
    } else {
#pragma unroll
      for (int k = 0; k < SPB; ++k) {
        const int t = 255 - b * SPB - k;
        if (t < HALF) break;
        const int off = (SPB - 1 - k) * 9;
        float xv[9];
#pragma unroll
        for (int j = 0; j < 9; ++j) xv[j] = lxb[off + j];
        float w[9];
#pragma unroll
        for (int j = 0; j < 9; ++j) w[j] = fexp(xv[j]) * st[j];
        float acc[9];
#pragma unroll
        for (int i = 0; i < 9; ++i) {
          float a = E[i][0] * w[0];
#pragma unroll
          for (int j = 1; j < 9; ++j) a = fmaf(E[i][j], w[j], a);
          acc[i] = a;
        }
#pragma unroll
        for (int i = 0; i < 9; ++i) st[i] = acc[i];
        emit += lxb[off + pcur];                    // x_t[p_t]
        const int pm = pl[plbase + (t - 1 - 127)];  // p_{t-1}
        trn += ltran[pm * 9 + pcur];
        pcur = pm;
        if (((255 - t) & 7) == 7) {
          float m = st[0];
#pragma unroll
          for (int i = 1; i < 9; ++i) m = fmaxf(m, st[i]);
          const int ex = (int)((__float_as_uint(m) >> 23) & 0xffu) - 126;
          ce += ex;
          const float sc = __uint_as_float((unsigned)(127 - ex) << 23);
#pragma unroll
          for (int i = 0; i < 9; ++i) st[i] *= sc;
        }
      }
    }
  }

  // ---- write partials (field-major: coalesced)
  float* wp = ws + seq;
  if (fwd) {
#pragma unroll
    for (int i = 0; i < 9; ++i) wp[i * B_N] = st[i];
    wp[9 * B_N] = (float)ce;
    const int p0 = pl[plbase];
    wp[10 * B_N] = emit + trn + initv[p0];
  } else {
#pragma unroll
    for (int i = 0; i < 9; ++i) wp[(11 + i) * B_N] = st[i];
    wp[20 * B_N] = (float)ce;
    wp[21 * B_N] = emit + trn;
  }
}

__global__ __launch_bounds__(256) void crf_combine(
    const float* __restrict__ ws, float* __restrict__ out)
{
  const int s = blockIdx.x * 256 + threadIdx.x;
  float dot = 0.f;
#pragma unroll
  for (int i = 0; i < 9; ++i)
    dot = fmaf(ws[i * B_N + s], ws[(11 + i) * B_N + s], dot);
  const float score =
      (__builtin_amdgcn_logf(dot) + ws[9 * B_N + s] + ws[20 * B_N + s]) * LN2f;
  out[s] = score - (ws[10 * B_N + s] + ws[21 * B_N + s]);
}

extern "C" void kernel_launch(void* const* d_in, const int* in_sizes, int n_in,
                              void* d_out, int out_size, void* d_ws, size_t ws_size,
                              hipStream_t stream) {
  (void)in_sizes; (void)n_in; (void)out_size; (void)ws_size;
  const float* xg    = (const float*)d_in[0];
  const int*   path  = (const int*)d_in[1];
  const float* tran  = (const float*)d_in[2];
  const float* initv = (const float*)d_in[3];
  float* ws  = (float*)d_ws;    // needs 22*8192*4 = 721 KB
  float* out = (float*)d_out;

  crf_half<<<2 * NDIR_BLOCKS, 64, 0, stream>>>(xg, path, tran, initv, ws);
  crf_combine<<<B_N / 256, 256, 0, stream>>>(ws, out);
}

// Round 4
// 147.480 us; speedup vs baseline: 1.2181x; 1.0373x over previous
//
#include <hip/hip_runtime.h>

// SimpleCRFHead R4: lane-per-sequence f32 forward-backward split, ILP-restructured.
// Per 6-step block: hoist ALL LDS reads + 54 exps + path/emit/tran gathers to the
// block head; the only chained work left is six 9x9 matvecs (crit path ~9 FMA/step).
// Matvec packed into float2 to trigger v_pk_fma_f32 (full-rate packed fp32).
// 256 blocks x 1 wave; 1 wave/CU -> VGPRs are free, latency must be hidden by ILP.

#define B_N 8192
#define L_N 256
#define SEQ_STRIDE 2304      // L_N * 9
#define HALF 128
#define SPB 6                // steps per x block
#define XW 54                // floats per seq per x block
#define XSTRIDE 55           // odd -> 2-way-free LDS banks
#define NBLK 22              // ceil(128/6)
#define PLS 129              // path LDS row stride
#define NDIR_BLOCKS (B_N / 64)

#define LOG2E 1.44269504088896340736f
#define LN2f  0.69314718055994530942f

typedef __attribute__((ext_vector_type(2))) float f32x2;

__device__ __forceinline__ void gl_lds4(const void* g, void* l) {
  __builtin_amdgcn_global_load_lds(
      (const __attribute__((address_space(1))) void*)g,
      (__attribute__((address_space(3))) void*)l, 4, 0, 0);
}

__device__ __forceinline__ float fexp(float x) {
  return __builtin_amdgcn_exp2f(x * LOG2E);   // v_exp_f32 = 2^x
}

__global__ __launch_bounds__(64) void crf_half(
    const float* __restrict__ xg, const int* __restrict__ path,
    const float* __restrict__ tran, const float* __restrict__ initv,
    float* __restrict__ ws)
{
  __shared__ float lx[2][64 * XSTRIDE];
  __shared__ int   pl[64 * PLS];
  __shared__ float ltran[81];

  const int lane = threadIdx.x;
  const bool fwd = (int)blockIdx.x < NDIR_BLOCKS;
  const int seq0 = (fwd ? blockIdx.x : blockIdx.x - NDIR_BLOCKS) * 64;
  const int seq  = seq0 + lane;

  for (int i = lane; i < 81; i += 64) ltran[i] = tran[i];

  // ---- stage path: fwd t in [0,127]; bwd t in [127,255] (+255 at slot 128)
  {
    const int t0 = fwd ? 0 : 127;
    const int* g = path + (size_t)seq0 * L_N + t0 + lane;
    for (int ss = 0; ss < 64; ++ss) {
      gl_lds4(g,      &pl[ss * PLS]);
      gl_lds4(g + 64, &pl[ss * PLS + 64]);
      g += L_N;
    }
    if (!fwd && lane == 0) {
      const int* g2 = path + (size_t)seq0 * L_N + 255;
      for (int ss = 0; ss < 64; ++ss) {
        gl_lds4(g2, &pl[ss * PLS + 128]);
        g2 += L_N;
      }
    }
  }

  // ---- stage x block 0
  if (lane < XW) {
    const int fbase = fwd ? 0 : (SEQ_STRIDE - XW);
    const float* g = xg + (size_t)seq0 * SEQ_STRIDE + fbase + lane;
    for (int ss = 0; ss < 64; ++ss) {
      gl_lds4(g, &lx[0][ss * XSTRIDE]);
      g += SEQ_STRIDE;
    }
  }

  // ---- packed transition coefficients (prologue only).
  // fwd: out_i = sum_j E[i][j]*st[j],  E[i][j] = e^{tran[j*9+i]}
  // bwd: u_i   = sum_j E[i][j]*w[j],   E[i][j] = e^{tran[i*9+j]}
  // EP[j][i2] = (E[2*i2][j], E[2*i2+1][j]);  E8[j] = E[8][j]
  f32x2 EP[9][4];
  float E8[9];
#pragma unroll
  for (int j = 0; j < 9; ++j) {
#pragma unroll
    for (int i2 = 0; i2 < 4; ++i2) {
      float v0 = fexp(fwd ? tran[j * 9 + 2 * i2]     : tran[(2 * i2) * 9 + j]);
      float v1 = fexp(fwd ? tran[j * 9 + 2 * i2 + 1] : tran[(2 * i2 + 1) * 9 + j]);
      EP[j][i2] = (f32x2){v0, v1};
    }
    E8[j] = fexp(fwd ? tran[j * 9 + 8] : tran[8 * 9 + j]);
  }

  float st[9];
  float emit = 0.f, trn = 0.f;
  int ce = 0, pcur = 0;

  asm volatile("s_waitcnt vmcnt(0)" ::: "memory");

  if (!fwd) {
#pragma unroll
    for (int i = 0; i < 9; ++i) st[i] = 1.f;
    pcur = pl[lane * PLS + 128];   // p_255
  }

  const int plbase = lane * PLS;
  const int xrow   = lane * XSTRIDE;

#pragma unroll 1
  for (int b = 0; b < NBLK; ++b) {
    asm volatile("s_waitcnt vmcnt(0)" ::: "memory");  // block b staged

    // prefetch block b+1 into other buffer
    if (b + 1 < NBLK && lane < XW) {
      const int fb = fwd ? (b + 1) * XW : (SEQ_STRIDE - XW * (b + 2));
      const float* g = xg + (size_t)seq0 * SEQ_STRIDE + fb + lane;
      float* dst = &lx[(b + 1) & 1][0];
      for (int ss = 0; ss < 64; ++ss) {
        gl_lds4(g, dst + ss * XSTRIDE);
        g += SEQ_STRIDE;
      }
    }

    const float* lxb = &lx[b & 1][xrow];

    // ---- phase 1: all 54 exps for this block (independent of recurrence)
    float e[XW];
#pragma unroll
    for (int q = 0; q < XW; ++q) e[q] = fexp(lxb[q]);

    if (fwd) {
      // ---- phase 2: path gathers for the whole block
      int pv[SPB];
#pragma unroll
      for (int k = 0; k < SPB; ++k) {
        const int t = b * SPB + k;
        pv[k] = (t < HALF) ? pl[plbase + t] : 0;
      }
#pragma unroll
      for (int k = 0; k < SPB; ++k) {
        const int t = b * SPB + k;
        if (t < HALF) {
          if (t == 0) {
            emit = lxb[pv[0]];
          } else {
            emit += lxb[k * 9 + pv[k]];
            trn  += ltran[pcur * 9 + pv[k]];
          }
          pcur = pv[k];
        }
      }
      // ---- phase 3: chained matvecs only
#pragma unroll
      for (int k = 0; k < SPB; ++k) {
        const int t = b * SPB + k;
        if (t < HALF) {
          if (t == 0) {
#pragma unroll
            for (int i = 0; i < 9; ++i) st[i] = fexp(initv[i] + lxb[i]);
          } else {
            const int o = k * 9;
            f32x2 a0 = EP[0][0] * st[0], a1 = EP[0][1] * st[0],
                  a2 = EP[0][2] * st[0], a3 = EP[0][3] * st[0];
            float a8 = E8[0] * st[0];
#pragma unroll
            for (int j = 1; j < 9; ++j) {
              a0 += EP[j][0] * st[j]; a1 += EP[j][1] * st[j];
              a2 += EP[j][2] * st[j]; a3 += EP[j][3] * st[j];
              a8 = fmaf(E8[j], st[j], a8);
            }
            st[0] = a0.x * e[o + 0]; st[1] = a0.y * e[o + 1];
            st[2] = a1.x * e[o + 2]; st[3] = a1.y * e[o + 3];
            st[4] = a2.x * e[o + 4]; st[5] = a2.y * e[o + 5];
            st[6] = a3.x * e[o + 6]; st[7] = a3.y * e[o + 7];
            st[8] = a8 * e[o + 8];
          }
        }
      }
    } else {
      // ---- phase 2: path gathers (t descending: t = 255 - b*SPB - k)
#pragma unroll
      for (int k = 0; k < SPB; ++k) {
        const int t = 255 - b * SPB - k;
        if (t >= HALF) {
          const int o = (SPB - 1 - k) * 9;
          emit += lxb[o + pcur];                 // x_t[p_t]
          const int pm = pl[plbase + (t - HALF)]; // p_{t-1}
          trn += ltran[pm * 9 + pcur];
          pcur = pm;
        }
      }
      // ---- phase 3: chained matvecs
#pragma unroll
      for (int k = 0; k < SPB; ++k) {
        const int t = 255 - b * SPB - k;
        if (t >= HALF) {
          const int o = (SPB - 1 - k) * 9;
          float w[9];
#pragma unroll
          for (int j = 0; j < 9; ++j) w[j] = e[o + j] * st[j];
          f32x2 a0 = EP[0][0] * w[0], a1 = EP[0][1] * w[0],
                a2 = EP[0][2] * w[0], a3 = EP[0][3] * w[0];
          float a8 = E8[0] * w[0];
#pragma unroll
          for (int j = 1; j < 9; ++j) {
            a0 += EP[j][0] * w[j]; a1 += EP[j][1] * w[j];
            a2 += EP[j][2] * w[j]; a3 += EP[j][3] * w[j];
            a8 = fmaf(E8[j], w[j], a8);
          }
          st[0] = a0.x; st[1] = a0.y; st[2] = a1.x; st[3] = a1.y;
          st[4] = a2.x; st[5] = a2.y; st[6] = a3.x; st[7] = a3.y;
          st[8] = a8;
        }
      }
    }

    // ---- rescale once per block (growth <= ~2^66 per 6 steps, safe in f32)
    float m = st[0];
#pragma unroll
    for (int i = 1; i < 9; ++i) m = fmaxf(m, st[i]);
    const int ex = (int)((__float_as_uint(m) >> 23) & 0xffu) - 126;
    ce += ex;
    const float sc = __uint_as_float((unsigned)(127 - ex) << 23);
#pragma unroll
    for (int i = 0; i < 9; ++i) st[i] *= sc;
  }

  // ---- write partials (field-major: coalesced)
  float* wp = ws + seq;
  if (fwd) {
#pragma unroll
    for (int i = 0; i < 9; ++i) wp[i * B_N] = st[i];
    wp[9 * B_N] = (float)ce;
    const int p0 = pl[plbase];
    wp[10 * B_N] = emit + trn + initv[p0];
  } else {
#pragma unroll
    for (int i = 0; i < 9; ++i) wp[(11 + i) * B_N] = st[i];
    wp[20 * B_N] = (float)ce;
    wp[21 * B_N] = emit + trn;
  }
}

__global__ __launch_bounds__(256) void crf_combine(
    const float* __restrict__ ws, float* __restrict__ out)
{
  const int s = blockIdx.x * 256 + threadIdx.x;
  float dot = 0.f;
#pragma unroll
  for (int i = 0; i < 9; ++i)
    dot = fmaf(ws[i * B_N + s], ws[(11 + i) * B_N + s], dot);
  const float score =
      (__builtin_amdgcn_logf(dot) + ws[9 * B_N + s] + ws[20 * B_N + s]) * LN2f;
  out[s] = score - (ws[10 * B_N + s] + ws[21 * B_N + s]);
}

extern "C" void kernel_launch(void* const* d_in, const int* in_sizes, int n_in,
                              void* d_out, int out_size, void* d_ws, size_t ws_size,
                              hipStream_t stream) {
  (void)in_sizes; (void)n_in; (void)out_size; (void)ws_size;
  const float* xg    = (const float*)d_in[0];
  const int*   path  = (const int*)d_in[1];
  const float* tran  = (const float*)d_in[2];
  const float* initv = (const float*)d_in[3];
  float* ws  = (float*)d_ws;    // 22*8192*4 = 721 KB
  float* out = (float*)d_out;

  crf_half<<<2 * NDIR_BLOCKS, 64, 0, stream>>>(xg, path, tran, initv, ws);
  crf_combine<<<B_N / 256, 256, 0, stream>>>(ws, out);
}

// Round 5
// 133.705 us; speedup vs baseline: 1.3436x; 1.1030x over previous
//
#include <hip/hip_runtime.h>

// SimpleCRFHead R5: quad-split (4 lanes per sequence) f32 forward-backward.
// 1024 blocks x 64 threads -> 1 wave/SIMD machine-wide (vs 1 wave per 4 SIMDs
// in R4). Lane c of each quad owns states 3c..3c+2 (c==3: zero pad).
// Per step: 9 quad_perm DPP movs broadcast the 9-state vector, 36 FMA compute
// this lane's 3 outputs. DPP is VALU-latency cross-lane (not LDS). Rescale is
// lane-local on the replicated state. Path/emit/tran reads are quad-uniform
// LDS broadcasts. f32 end-to-end.

#define B_N 8192
#define L_N 256
#define SEQ_STRIDE 2304      // L_N * 9
#define HALF 128
#define SPB 6                // steps per x window
#define XW 54                // floats per seq per window
#define XSTRIDE 55           // odd -> conflict-free LDS banks
#define NBLK 22              // ceil(128/6)
#define PLS 129              // path LDS row stride
#define SPW 16               // seqs per wave
#define NDIR_BLOCKS (B_N / SPW)   // 512 per direction

#define LOG2E 1.44269504088896340736f
#define LN2f  0.69314718055994530942f

// quad_perm rotate-left-by-r: lane c receives quad-lane (c+r)&3
#define QP1 57    // perm(1,2,3,0)
#define QP2 78    // perm(2,3,0,1)
#define QP3 147   // perm(3,0,1,2)
#define QROT(src, CTRL) \
  __int_as_float(__builtin_amdgcn_mov_dpp(__float_as_int(src), CTRL, 0xf, 0xf, 0))

__device__ __forceinline__ void gl_lds4(const void* g, void* l) {
  __builtin_amdgcn_global_load_lds(
      (const __attribute__((address_space(1))) void*)g,
      (__attribute__((address_space(3))) void*)l, 4, 0, 0);
}

__device__ __forceinline__ float fexp(float x) {
  return __builtin_amdgcn_exp2f(x * LOG2E);   // v_exp_f32 = 2^x
}

__global__ __launch_bounds__(64, 1) void crf_half(
    const float* __restrict__ xg, const int* __restrict__ path,
    const float* __restrict__ tran, const float* __restrict__ initv,
    float* __restrict__ ws)
{
  __shared__ float lx[2][SPW * XSTRIDE];  // 7040 B
  __shared__ int   pl[SPW * PLS];         // 8256 B
  __shared__ int   pl255[SPW];
  __shared__ float ltran[81];             // ~15.7 KB total -> 4 blocks/CU

  const int lane = threadIdx.x;
  const int c = lane & 3;                 // quad slot (state group)
  const int q = lane >> 2;                // seq slot within wave (0..15)
  const bool fwd = (int)blockIdx.x < NDIR_BLOCKS;
  const int seq0 = (fwd ? blockIdx.x : blockIdx.x - NDIR_BLOCKS) * SPW;

  for (int i = lane; i < 81; i += 64) ltran[i] = tran[i];

  // ---- stage path rows (gl_lds, coalesced 64-wide)
  {
    const int t0 = fwd ? 0 : 127;
#pragma unroll
    for (int r = 0; r < SPW; ++r) {
      const int* g = path + (size_t)(seq0 + r) * L_N + t0 + lane;
      gl_lds4(g,      &pl[r * PLS]);
      gl_lds4(g + 64, &pl[r * PLS + 64]);
    }
  }
  if (!fwd && lane < SPW)
    pl255[lane] = path[(size_t)(seq0 + lane) * L_N + 255];

  // ---- stage x window 0
  if (lane < XW) {
    const int fb = fwd ? 0 : (SEQ_STRIDE - XW);
#pragma unroll
    for (int r = 0; r < SPW; ++r)
      gl_lds4(xg + (size_t)(seq0 + r) * SEQ_STRIDE + fb + lane,
              &lx[0][r * XSTRIDE]);
  }

  // ---- rotation-ordered transition coefficients (prologue only)
  // fwd: out_i = sum_j E[i][j]*st[j], E[i][j]=e^{tran[j*9+i]}
  // bwd: out_i = sum_j E[i][j]*w[j],  E[i][j]=e^{tran[i*9+j]}
  // Erot[r][k][i]: coefficient for (own output i, rotation r, partner reg k)
  float Erot[4][3][3];
#pragma unroll
  for (int r = 0; r < 4; ++r)
#pragma unroll
    for (int k = 0; k < 3; ++k)
#pragma unroll
      for (int i = 0; i < 3; ++i) {
        const int ig = 3 * c + i;
        const int jg = 3 * ((c + r) & 3) + k;
        float v = 0.f;
        if (ig < 9 && jg < 9)
          v = fexp(fwd ? tran[jg * 9 + ig] : tran[ig * 9 + jg]);
        Erot[r][k][i] = v;
      }

  float o[3];                 // own 3 states (c==3: always 0)
  float emit = 0.f, trn = 0.f;
  int ce = 0, pcur = 0;

  if (!fwd) {
#pragma unroll
    for (int k = 0; k < 3; ++k) o[k] = (c < 3) ? 1.f : 0.f;
    pcur = pl255[q];          // p_255
  }

  const int myoff = (c == 3) ? 0 : 3 * c;   // c==3 reads safe dummy region

#pragma unroll 1
  for (int b = 0; b < NBLK; ++b) {
    asm volatile("s_waitcnt vmcnt(0)" ::: "memory");  // window b staged

    // prefetch window b+1
    if (b + 1 < NBLK && lane < XW) {
      const int fb = fwd ? (b + 1) * XW : (SEQ_STRIDE - XW * (b + 2));
      float* dst = &lx[(b + 1) & 1][0];
#pragma unroll
      for (int r = 0; r < SPW; ++r)
        gl_lds4(xg + (size_t)(seq0 + r) * SEQ_STRIDE + fb + lane,
                dst + r * XSTRIDE);
    }

    const float* lxq = &lx[b & 1][q * XSTRIDE];

    // ---- own-state exps for the whole window (3 per step)
    float e[SPB * 3];
#pragma unroll
    for (int tt = 0; tt < SPB; ++tt)
#pragma unroll
      for (int k = 0; k < 3; ++k)
        e[tt * 3 + k] = fexp(lxq[tt * 9 + myoff + k]);

    if (fwd) {
#pragma unroll
      for (int kk = 0; kk < SPB; ++kk) {
        const int t = b * SPB + kk;
        if (t < HALF) {
          if (t == 0) {
#pragma unroll
            for (int k = 0; k < 3; ++k)
              o[k] = (c < 3) ? fexp(initv[3 * c + k] + lxq[myoff + k]) : 0.f;
            pcur = pl[q * PLS];
            emit = lxq[pcur];
          } else {
            // exchange st -> replicated g[r][k] = st[3*((c+r)&3)+k]
            float g[4][3];
#pragma unroll
            for (int k = 0; k < 3; ++k) {
              g[0][k] = o[k];
              g[1][k] = QROT(o[k], QP1);
              g[2][k] = QROT(o[k], QP2);
              g[3][k] = QROT(o[k], QP3);
            }
            if (kk == 0 && b > 0) {   // rescale once per window (6 steps)
              float m = g[0][0];
#pragma unroll
              for (int r = 0; r < 4; ++r)
#pragma unroll
                for (int k = 0; k < 3; ++k) m = fmaxf(m, g[r][k]);
              const int ex = (int)((__float_as_uint(m) >> 23) & 0xffu) - 126;
              ce += ex;
              const float sc = __uint_as_float((unsigned)(127 - ex) << 23);
#pragma unroll
              for (int r = 0; r < 4; ++r)
#pragma unroll
                for (int k = 0; k < 3; ++k) g[r][k] *= sc;
            }
            float out[3];
#pragma unroll
            for (int i = 0; i < 3; ++i) {
              float a = Erot[0][0][i] * g[0][0];
#pragma unroll
              for (int r = 0; r < 4; ++r)
#pragma unroll
                for (int k = 0; k < 3; ++k)
                  if (r + k > 0) a = fmaf(Erot[r][k][i], g[r][k], a);
              out[i] = a;
            }
            // path score (quad-uniform LDS broadcasts)
            const int p = pl[q * PLS + t];
            emit += lxq[kk * 9 + p];
            trn  += ltran[pcur * 9 + p];
            pcur = p;
#pragma unroll
            for (int i = 0; i < 3; ++i) o[i] = out[i] * e[kk * 3 + i];
          }
        }
      }
    } else {
#pragma unroll
      for (int kk = 0; kk < SPB; ++kk) {
        const int t = 255 - b * SPB - kk;
        if (t >= HALF) {
          const int tt = SPB - 1 - kk;
          float w[3];
#pragma unroll
          for (int k = 0; k < 3; ++k) w[k] = e[tt * 3 + k] * o[k];
          float g[4][3];
#pragma unroll
          for (int k = 0; k < 3; ++k) {
            g[0][k] = w[k];
            g[1][k] = QROT(w[k], QP1);
            g[2][k] = QROT(w[k], QP2);
            g[3][k] = QROT(w[k], QP3);
          }
          if (kk == 0 && b > 0) {
            float m = g[0][0];
#pragma unroll
            for (int r = 0; r < 4; ++r)
#pragma unroll
              for (int k = 0; k < 3; ++k) m = fmaxf(m, g[r][k]);
            const int ex = (int)((__float_as_uint(m) >> 23) & 0xffu) - 126;
            ce += ex;
            const float sc = __uint_as_float((unsigned)(127 - ex) << 23);
#pragma unroll
            for (int r = 0; r < 4; ++r)
#pragma unroll
              for (int k = 0; k < 3; ++k) g[r][k] *= sc;
          }
#pragma unroll
          for (int i = 0; i < 3; ++i) {
            float a = Erot[0][0][i] * g[0][0];
#pragma unroll
            for (int r = 0; r < 4; ++r)
#pragma unroll
              for (int k = 0; k < 3; ++k)
                if (r + k > 0) a = fmaf(Erot[r][k][i], g[r][k], a);
            o[i] = a;
          }
          // path score: emit for t, tran pair (p_{t-1}, p_t)
          emit += lxq[tt * 9 + pcur];
          const int pm = pl[q * PLS + (t - 1 - 127)];
          trn += ltran[pm * 9 + pcur];
          pcur = pm;
        }
      }
    }
  }

  // ---- write partials (field-major)
  const int sq = seq0 + q;
  float* wp = ws + sq;
  if (fwd) {
    if (c < 3) {
#pragma unroll
      for (int k = 0; k < 3; ++k) wp[(3 * c + k) * B_N] = o[k];
    } else {
      wp[9 * B_N] = (float)ce;
      const int p0 = pl[q * PLS];
      wp[10 * B_N] = emit + trn + initv[p0];
    }
  } else {
    if (c < 3) {
#pragma unroll
      for (int k = 0; k < 3; ++k) wp[(11 + 3 * c + k) * B_N] = o[k];
    } else {
      wp[20 * B_N] = (float)ce;
      wp[21 * B_N] = emit + trn;
    }
  }
}

__global__ __launch_bounds__(256) void crf_combine(
    const float* __restrict__ ws, float* __restrict__ out)
{
  const int s = blockIdx.x * 256 + threadIdx.x;
  float dot = 0.f;
#pragma unroll
  for (int i = 0; i < 9; ++i)
    dot = fmaf(ws[i * B_N + s], ws[(11 + i) * B_N + s], dot);
  const float score =
      (__builtin_amdgcn_logf(dot) + ws[9 * B_N + s] + ws[20 * B_N + s]) * LN2f;
  out[s] = score - (ws[10 * B_N + s] + ws[21 * B_N + s]);
}

extern "C" void kernel_launch(void* const* d_in, const int* in_sizes, int n_in,
                              void* d_out, int out_size, void* d_ws, size_t ws_size,
                              hipStream_t stream) {
  (void)in_sizes; (void)n_in; (void)out_size; (void)ws_size;
  const float* xg    = (const float*)d_in[0];
  const int*   path  = (const int*)d_in[1];
  const float* tran  = (const float*)d_in[2];
  const float* initv = (const float*)d_in[3];
  float* ws  = (float*)d_ws;    // 22*8192*4 = 721 KB
  float* out = (float*)d_out;

  crf_half<<<2 * NDIR_BLOCKS, 64, 0, stream>>>(xg, path, tran, initv, ws);
  crf_combine<<<B_N / 256, 256, 0, stream>>>(ws, out);
}